// Round 14
// baseline (97.287 us; speedup 1.0000x reference)
//
#include <hip/hip_runtime.h>
#include <hip/hip_bf16.h>

// Problem: T=2048, B=32, H=512
//   scores[b,t] = sum_o v[o] * tanh( hb[b,o] + sum_h enc[t,b,h] * W2[o,h] )
//   out[b,0,t]  = softmax_t(scores[b,:])
//
// HARD-WON RULES (R2..R13):
//  - WRITE_SIZE >> 2MB == scratch spill; VGPR tripwire. Keep staging static.
//  - global_load_lds dest is wave-uniform + lane*16B; per-wave distinct dests.
//  - 128^2 2-phase structure ceiling ~83us (R10); occupancy x2 null (R13),
//    scheduling surgery negative (R11). This round: m201-style 8-phase 256^2.
// R14: BM=256 BN=256 BK=64, 512 thr / 8 waves (2Mx4N), wave tile 128x64,
// acc[8][4], LDS 132KB, 4 phases per K-step, stage tile s+1 during step s.

#define TT 2048
#define BB 32
#define HH 512

typedef __attribute__((ext_vector_type(8))) short bf16x8;
typedef __attribute__((ext_vector_type(4))) float f32x4;

#define VMWAIT_(N) asm volatile("s_waitcnt vmcnt(" #N ")" ::: "memory")
#define VMWAIT(N) VMWAIT_(N)
#define LGKM0() asm volatile("s_waitcnt lgkmcnt(0)" ::: "memory")
#define BARRIER() asm volatile("s_barrier" ::: "memory")

static __device__ __forceinline__ unsigned cvt2(float a, float b) {
    union { __hip_bfloat162 h; unsigned u; } cv;
    cv.h = __float22bfloat162_rn(make_float2(a, b));   // v_cvt_pk_bf16_f32
    return cv.u;
}

static __device__ __forceinline__ unsigned short f2bf(float f) {
    unsigned int u = __float_as_uint(f);
    unsigned int r = (u + 0x7FFFu + ((u >> 16) & 1u)) >> 16;  // RNE
    return (unsigned short)r;
}

// tanh(x) = 1 - 2/(1+e^{2x});  inf-safe at both ends.
static __device__ __forceinline__ float fast_tanh(float x) {
    float e = __expf(2.0f * x);
    return 1.0f - 2.0f * __builtin_amdgcn_rcpf(1.0f + e);
}

static __device__ __forceinline__ void gload_lds16(const void* g, void* l) {
    __builtin_amdgcn_global_load_lds(
        (const __attribute__((address_space(1))) unsigned int*)g,
        (__attribute__((address_space(3))) unsigned int*)l, 16, 0, 0);
}

// ---- Kernel 1: pack W2 (= W_attn[:, 512:1024]) into the swizzled LDS image.
// idx = (((nt*8 + kt)*2 + h)*128 + j)*64 + c  (shorts)
// element = W2[o = nt*256 + h*128 + j][k = kt*64 + (c ^ ((j&7)<<3))]
__global__ void pack_w2_kernel(const float* __restrict__ W, short* __restrict__ W2p) {
    int idx = blockIdx.x * 256 + threadIdx.x;      // 262144 total
    int c  = idx & 63;
    int j  = (idx >> 6) & 127;
    int h  = (idx >> 13) & 1;
    int kt = (idx >> 14) & 7;
    int nt = idx >> 17;
    int o  = nt * 256 + h * 128 + j;
    int k  = kt * 64 + (c ^ ((j & 7) << 3));
    W2p[idx] = (short)f2bf(W[o * 1024 + 512 + k]);
}

// ---- Kernel 2: hb[b][o] = b_attn[o] + sum_h hidden[b,h] * W_attn[o,h]
__global__ void hb_kernel(const float* __restrict__ hidden, const float* __restrict__ W,
                          const float* __restrict__ b_attn, float* __restrict__ hb) {
    __shared__ float hrow[512];
    int b = blockIdx.x >> 1;
    int o = ((blockIdx.x & 1) << 8) + threadIdx.x;
    for (int h = threadIdx.x; h < 512; h += 256) hrow[h] = hidden[b * 512 + h];
    __syncthreads();
    const float4* wr = reinterpret_cast<const float4*>(W + (size_t)o * 1024);
    const float4* hr = reinterpret_cast<const float4*>(hrow);
    float acc = b_attn[o];
#pragma unroll 8
    for (int i = 0; i < 128; ++i) {
        float4 w = wr[i], h4 = hr[i];
        acc += w.x * h4.x + w.y * h4.y + w.z * h4.z + w.w * h4.w;
    }
    hb[b * 512 + o] = acc;
}

// ---- Kernel 3: 256x256-tile 8-phase GEMM + fused tanh/v-dot epilogue.
// Grid: 512 blocks, XCD remap w=(bid&7)*64+(bid>>3); nt=w&1, mtile=w>>1.
// mtile: b = mtile>>3, t0 = (mtile&7)*256.
// 512 threads = 8 waves (wm 0..1 x wn 0..3), wave tile 128x64, acc[8][4].
// K = 512 as 8 K-steps of 64; step s = 4 phases (one C-quadrant each);
// tile s+1 staged during step s into buf (s+1)&1 (freed at end of step s-1):
//   ph0: A flat loads + B half0 gload ; ph1: B half1 gload ; ph3: vmcnt(0)+A write.
__global__ __launch_bounds__(512, 2) void attn_main_kernel(
    const float* __restrict__ enc, const short* __restrict__ W2p,
    const float* __restrict__ hb, const float* __restrict__ v,
    float* __restrict__ scores_part)
{
    __shared__ short As[2][2][128 * 64];   // [dbuf][M-half][row][k], swizzled k
    __shared__ short Bs[2][2][128 * 64];   // [dbuf][N-half][row][k], pre-swizzled image
    __shared__ float s_red[4][256];

    const int tid = threadIdx.x;
    const int bid = blockIdx.x;
    const int w = (bid & 7) * 64 + (bid >> 3);   // bijective (512 % 8 == 0)
    const int nt = w & 1;                 // 2 N-tiles of 256 cols
    const int mtile = w >> 1;             // 256 M-tiles
    const int b = mtile >> 3;
    const int t0 = (mtile & 7) * 256;

    const int wave = tid >> 6;
    const int lane = tid & 63;
    const int wm = wave >> 2;             // 0..1 : 128-row half
    const int wn = wave & 3;              // 0..3 : 64-col quarter
    const int lcol = lane & 15;
    const int lq = lane >> 4;

    // A staging: thread covers row ar of BOTH M-halves, float cols afc..afc+15
    const int ar = tid >> 2;              // 0..127
    const int afc = (tid & 3) * 16;       // 0,16,32,48
    const float* enc0 = enc + ((size_t)(t0 + ar) * BB + b) * HH + afc;
    const float* enc1 = enc0 + (size_t)128 * BB * HH;
    // B staging: wave covers rows wave*16..+16 of each packed half
    const short* bsrc = W2p + (size_t)nt * 131072 + wave * 1024 + lane * 8;

    f32x4 acc[8][4];
#pragma unroll
    for (int i = 0; i < 8; ++i)
#pragma unroll
        for (int j = 0; j < 4; ++j) acc[i][j] = (f32x4){0.f, 0.f, 0.f, 0.f};

    float4 rA[8];

#define SA_LOAD(KT)                                                                 \
    {                                                                               \
        const float* s0 = enc0 + (KT) * 64;                                         \
        const float* s1 = enc1 + (KT) * 64;                                         \
        rA[0] = *reinterpret_cast<const float4*>(s0);                               \
        rA[1] = *reinterpret_cast<const float4*>(s0 + 4);                           \
        rA[2] = *reinterpret_cast<const float4*>(s0 + 8);                           \
        rA[3] = *reinterpret_cast<const float4*>(s0 + 12);                          \
        rA[4] = *reinterpret_cast<const float4*>(s1);                               \
        rA[5] = *reinterpret_cast<const float4*>(s1 + 4);                           \
        rA[6] = *reinterpret_cast<const float4*>(s1 + 8);                           \
        rA[7] = *reinterpret_cast<const float4*>(s1 + 12);                          \
    }

#define SB(KT, BI2, HB)                                                             \
    {                                                                               \
        const short* s0 = bsrc + ((KT) * 2 + (HB)) * 8192;                          \
        gload_lds16(s0,       &Bs[BI2][HB][(wave * 16) * 64]);                      \
        gload_lds16(s0 + 512, &Bs[BI2][HB][(wave * 16 + 8) * 64]);                  \
    }

#define SA_WRITE(BI2)                                                               \
    {                                                                               \
        uint4 q0, q1, q2, q3;                                                       \
        q0.x = cvt2(rA[0].x, rA[0].y);  q0.y = cvt2(rA[0].z, rA[0].w);              \
        q0.z = cvt2(rA[1].x, rA[1].y);  q0.w = cvt2(rA[1].z, rA[1].w);              \
        q1.x = cvt2(rA[2].x, rA[2].y);  q1.y = cvt2(rA[2].z, rA[2].w);              \
        q1.z = cvt2(rA[3].x, rA[3].y);  q1.w = cvt2(rA[3].z, rA[3].w);              \
        q2.x = cvt2(rA[4].x, rA[4].y);  q2.y = cvt2(rA[4].z, rA[4].w);              \
        q2.z = cvt2(rA[5].x, rA[5].y);  q2.w = cvt2(rA[5].z, rA[5].w);              \
        q3.x = cvt2(rA[6].x, rA[6].y);  q3.y = cvt2(rA[6].z, rA[6].w);              \
        q3.z = cvt2(rA[7].x, rA[7].y);  q3.w = cvt2(rA[7].z, rA[7].w);              \
        const int sw = (ar & 7) << 3;                                               \
        *reinterpret_cast<uint4*>(&As[BI2][0][ar * 64 + (afc ^ sw)]) = q0;          \
        *reinterpret_cast<uint4*>(&As[BI2][0][ar * 64 + ((afc + 8) ^ sw)]) = q1;    \
        *reinterpret_cast<uint4*>(&As[BI2][1][ar * 64 + (afc ^ sw)]) = q2;          \
        *reinterpret_cast<uint4*>(&As[BI2][1][ar * 64 + ((afc + 8) ^ sw)]) = q3;    \
    }

#define PHASE(BI, QM, QN, PRE)                                                      \
    {                                                                               \
        bf16x8 af[4][2], bq[2][2];                                                  \
        _Pragma("unroll")                                                           \
        for (int mt = 0; mt < 4; ++mt) {                                            \
            const int rr = ((QM) * 4 + mt) * 16 + lcol;                             \
            _Pragma("unroll")                                                       \
            for (int kk = 0; kk < 2; ++kk)                                          \
                af[mt][kk] = *reinterpret_cast<const bf16x8*>(                      \
                    &As[BI][wm][rr * 64 + ((kk * 32 + lq * 8) ^ ((lcol & 7) << 3))]); \
        }                                                                           \
        _Pragma("unroll")                                                           \
        for (int ns = 0; ns < 2; ++ns) {                                            \
            const int j = (wn & 1) * 64 + ((QN) * 2 + ns) * 16 + lcol;              \
            _Pragma("unroll")                                                       \
            for (int kk = 0; kk < 2; ++kk)                                          \
                bq[ns][kk] = *reinterpret_cast<const bf16x8*>(                      \
                    &Bs[BI][wn >> 1][j * 64 + ((kk * 32 + lq * 8) ^ ((j & 7) << 3))]); \
        }                                                                           \
        PRE;                                                                        \
        BARRIER();                                                                  \
        LGKM0();                                                                    \
        __builtin_amdgcn_sched_barrier(0);                                          \
        __builtin_amdgcn_s_setprio(1);                                              \
        _Pragma("unroll")                                                           \
        for (int mt = 0; mt < 4; ++mt)                                              \
            _Pragma("unroll")                                                       \
            for (int ns = 0; ns < 2; ++ns)                                          \
                _Pragma("unroll")                                                   \
                for (int kk = 0; kk < 2; ++kk)                                      \
                    acc[(QM) * 4 + mt][(QN) * 2 + ns] =                             \
                        __builtin_amdgcn_mfma_f32_16x16x32_bf16(                    \
                            af[mt][kk], bq[ns][kk],                                 \
                            acc[(QM) * 4 + mt][(QN) * 2 + ns], 0, 0, 0);            \
        __builtin_amdgcn_s_setprio(0);                                              \
        BARRIER();                                                                  \
    }

#define STEP_FULL(BI, KTN)                                                          \
    PHASE(BI, 0, 0, { SA_LOAD(KTN); SB(KTN, (BI) ^ 1, 0); })                        \
    PHASE(BI, 0, 1, { SB(KTN, (BI) ^ 1, 1); })                                      \
    PHASE(BI, 1, 0, {})                                                             \
    PHASE(BI, 1, 1, { VMWAIT(0); SA_WRITE((BI) ^ 1); LGKM0(); })

#define STEP_TAIL(BI)                                                               \
    PHASE(BI, 0, 0, {})                                                             \
    PHASE(BI, 0, 1, {})                                                             \
    PHASE(BI, 1, 0, {})                                                             \
    PHASE(BI, 1, 1, {})

    // ---- prologue: stage tile 0 -> buf0, full drain
    SB(0, 0, 0);
    SB(0, 0, 1);
    SA_LOAD(0);
    VMWAIT(0);
    SA_WRITE(0);
    LGKM0();
    BARRIER();

    // ---- 8 K-steps; step s computes buf s&1, stages tile s+1 -> buf (s+1)&1
    STEP_FULL(0, 1)
    STEP_FULL(1, 2)
    STEP_FULL(0, 3)
    STEP_FULL(1, 4)
    STEP_FULL(0, 5)
    STEP_FULL(1, 6)
    STEP_FULL(0, 7)
    STEP_TAIL(1)

    // ---- epilogue: tanh + v-dot over this wave's 64 cols, reduce to rows
    float part[8][4];
#pragma unroll
    for (int ri = 0; ri < 8; ++ri)
#pragma unroll
        for (int jj = 0; jj < 4; ++jj) part[ri][jj] = 0.0f;

#pragma unroll
    for (int ci = 0; ci < 4; ++ci) {
        const int o = nt * 256 + wn * 64 + ci * 16 + lcol;
        const float hbv = hb[b * 512 + o];
        const float vv = v[o];
#pragma unroll
        for (int ri = 0; ri < 8; ++ri)
#pragma unroll
            for (int jj = 0; jj < 4; ++jj)
                part[ri][jj] = fmaf(fast_tanh(acc[ri][ci][jj] + hbv), vv, part[ri][jj]);
    }

#pragma unroll
    for (int off = 1; off < 16; off <<= 1)
#pragma unroll
        for (int ri = 0; ri < 8; ++ri)
#pragma unroll
            for (int jj = 0; jj < 4; ++jj)
                part[ri][jj] += __shfl_xor(part[ri][jj], off, 64);

    if (lcol == 0) {
#pragma unroll
        for (int ri = 0; ri < 8; ++ri)
#pragma unroll
            for (int jj = 0; jj < 4; ++jj)
                s_red[wn][wm * 128 + ri * 16 + lq * 4 + jj] = part[ri][jj];
    }
    __syncthreads();

    if (tid < 256)
        scores_part[((size_t)nt * BB + b) * TT + t0 + tid] =
            s_red[0][tid] + s_red[1][tid] + s_red[2][tid] + s_red[3][tid];
}

// ---- Kernel 4: sum 2 N-tile partials + softmax over T per b
__global__ void softmax_kernel(const float* __restrict__ sp, float* __restrict__ out) {
    __shared__ float wred[4];
    __shared__ float wsum[4];
    const int b = blockIdx.x;
    const int tid = threadIdx.x;   // 256
    float vals[8];
    float mx = -1e30f;
#pragma unroll
    for (int i = 0; i < 8; ++i) {
        const int t = i * 256 + tid;
        const float s = sp[(size_t)b * TT + t] + sp[((size_t)BB + b) * TT + t];
        vals[i] = s;
        mx = fmaxf(mx, s);
    }
#pragma unroll
    for (int off = 32; off; off >>= 1) mx = fmaxf(mx, __shfl_xor(mx, off, 64));
    if ((tid & 63) == 0) wred[tid >> 6] = mx;
    __syncthreads();
    mx = fmaxf(fmaxf(wred[0], wred[1]), fmaxf(wred[2], wred[3]));
    float s = 0.0f;
#pragma unroll
    for (int i = 0; i < 8; ++i) {
        vals[i] = __expf(vals[i] - mx);
        s += vals[i];
    }
#pragma unroll
    for (int off = 32; off; off >>= 1) s += __shfl_xor(s, off, 64);
    if ((tid & 63) == 0) wsum[tid >> 6] = s;
    __syncthreads();
    s = wsum[0] + wsum[1] + wsum[2] + wsum[3];
    const float inv = 1.0f / s;
#pragma unroll
    for (int i = 0; i < 8; ++i) out[b * TT + i * 256 + tid] = vals[i] * inv;
}

extern "C" void kernel_launch(void* const* d_in, const int* in_sizes, int n_in,
                              void* d_out, int out_size, void* d_ws, size_t ws_size,
                              hipStream_t stream) {
    const float* hidden = (const float*)d_in[0];   // (1,B,H)
    const float* enc    = (const float*)d_in[1];   // (T,B,H)
    const float* W      = (const float*)d_in[2];   // (H,2H)
    const float* b_attn = (const float*)d_in[3];   // (H,)
    const float* v      = (const float*)d_in[4];   // (H,)
    float* out = (float*)d_out;                    // (B,1,T)

    char* base = (char*)d_ws;
    short* W2p = (short*)base;                          // 512*512*2 = 524288 B
    float* hb  = (float*)(base + 524288);               // 32*512*4  =  65536 B
    float* sp  = (float*)(base + 589824);               // 2*32*2048*4 = 524288 B

    pack_w2_kernel<<<1024, 256, 0, stream>>>(W, W2p);
    hb_kernel<<<64, 256, 0, stream>>>(hidden, W, b_attn, hb);
    attn_main_kernel<<<512, 512, 0, stream>>>(enc, W2p, hb, v, sp);
    softmax_kernel<<<32, 256, 0, stream>>>(sp, out);
}